// Round 8
// baseline (5507.841 us; speedup 1.0000x reference)
//
#include <hip/hip_runtime.h>
#include <math.h>

typedef float f4 __attribute__((ext_vector_type(4)));

#define NT 512

// dword offsets in ws (bf16 h buffers: 16384 dwords = 64 KB each)
#define H00 0
#define H01 16384
#define H10 32768
#define H11 49152
#define PLOG 65536       // 16384 floats
#define FLAGS 81920      // 512 contiguous uints
#define X4 82432         // f4-aligned (82432*4 % 16 == 0); 512*256*32 f4 = 64 MB

__device__ __forceinline__ void ld_bf(unsigned& d, const unsigned* p) {
  // coherent (L1-bypass, L2-allowed) dword load; completion via counted vmcnt
  asm volatile("global_load_dword %0, %1, off sc0" : "=v"(d) : "v"(p));
}
__device__ __forceinline__ void ld_x4(f4& d, const f4* p) {
  asm volatile("global_load_dwordx4 %0, %1, off" : "=v"(d) : "v"(p));
}
__device__ __forceinline__ unsigned pack_bf16(float lo, float hi) {
  unsigned u;
  asm volatile("v_cvt_pk_bf16_f32 %0, %1, %2" : "=v"(u) : "v"(lo), "v"(hi));
  return u;  // low 16 = bf16(lo), high 16 = bf16(hi), RNE
}
__device__ __forceinline__ void st_cohf(float* p, float v) {
  __hip_atomic_store(p, v, __ATOMIC_RELAXED, __HIP_MEMORY_SCOPE_AGENT);
}
__device__ __forceinline__ void st_cohu(unsigned* p, unsigned v) {
  __hip_atomic_store(p, v, __ATOMIC_RELAXED, __HIP_MEMORY_SCOPE_AGENT);
}
__device__ __forceinline__ unsigned ld_flag(const unsigned* p) {
  return __hip_atomic_load(p, __ATOMIC_RELAXED, __HIP_MEMORY_SCOPE_AGENT);
}
__device__ __forceinline__ float hsum(f4 a) {
  return (a[0] + a[1]) + (a[2] + a[3]);
}
__device__ __forceinline__ float bflo(unsigned d) {
  return __uint_as_float(d << 16);
}
__device__ __forceinline__ float bfhi(unsigned d) {
  return __uint_as_float(d & 0xffff0000u);
}

// h0 fp32 [l][b][k] -> bf16 packed h[kp][b] (dword = k-pair); zero flags.
__global__ __launch_bounds__(256) void init_kernel(const float* __restrict__ h0,
                                                   float* __restrict__ ws) {
  int g = blockIdx.x * 256 + threadIdx.x;  // 0..32767
  int l = g >> 14;
  int rem = g & 16383;
  int b = rem >> 9;
  int kp = rem & 511;
  float lo = h0[l * 32768 + b * 1024 + 2 * kp];
  float hi = h0[l * 32768 + b * 1024 + 2 * kp + 1];
  unsigned* hb = (unsigned*)ws + (l ? H11 : H00);
  hb[kp * 32 + b] = pack_bf16(lo, hi);
  if (g < 512) ((unsigned*)ws)[FLAGS + g] = 0u;
}

// x[b][t][k] -> x4[t][kq][b] f4 (coalesced writes; one-time)
__global__ __launch_bounds__(256) void xpose_kernel(const float* __restrict__ x,
                                                    float* __restrict__ ws) {
  f4* x4 = (f4*)(ws + X4);
  const f4* xs = (const f4*)x;
  const int t = blockIdx.x;
  const int kqq = threadIdx.x >> 5;
  const int b = threadIdx.x & 31;
  #pragma unroll 4
  for (int i = 0; i < 32; ++i) {
    const int kq = kqq * 32 + i;
    f4 v = xs[((size_t)b * NT + t) * 256 + kq];
    x4[((size_t)t * 256 + kq) * 32 + b] = v;
  }
}

// 256 blocks; block bid owns cols bid*4..+3 of Whh0, Wih1, Whh1, Wih0.
__global__ __launch_bounds__(512, 1) void rnn_kernel(
    const float* __restrict__ bih0, const float* __restrict__ bhh0,
    const float* __restrict__ Whh0, const float* __restrict__ Wih0,
    const float* __restrict__ Wih1, const float* __restrict__ Whh1,
    const float* __restrict__ bih1, const float* __restrict__ bhh1,
    const float* __restrict__ Wcls, const float* __restrict__ bcls,
    float* __restrict__ out, float* ws) {
  extern __shared__ float smem[];
  f4* w4 = (f4*)smem;                    // 4096 f4 = 64 KB
  float* part = smem + 16384;            // 4096 floats: [kg 16][row 8][b 32]
  float* prebuf = smem + 20480;          // 2048 floats: [kg 16][r 4][b 32]

  const int bid = blockIdx.x, tid = threadIdx.x;
  const int b = tid & 31, kg = tid >> 5;     // kg 0..15
  const int kq0 = kg * 16;                   // f4 k-base (64 k per kg)

  unsigned* flags = (unsigned*)ws + FLAGS;
  unsigned* hball = (unsigned*)ws;
  const f4* x4p = (const f4*)(ws + X4);

  // stage 16 weight rows (4 per matrix)
  {
    const f4* s0 = (const f4*)Whh0 + (size_t)(bid * 4) * 256;
    const f4* s1 = (const f4*)Wih1 + (size_t)(bid * 4) * 256;
    const f4* s2 = (const f4*)Whh1 + (size_t)(bid * 4) * 256;
    const f4* s3 = (const f4*)Wih0 + (size_t)(bid * 4) * 256;
    for (int i = tid; i < 1024; i += 512) {
      w4[i] = s0[i]; w4[1024 + i] = s1[i];
      w4[2048 + i] = s2[i]; w4[3072 + i] = s3[i];
    }
  }

  const int rj = tid >> 5;                   // 0..7 valid when tid<256
  const int jcol = bid * 4 + (rj & 3);
  float bias = 0.f;
  if (tid < 256)
    bias = (rj < 4) ? (bih0[jcol] + bhh0[jcol]) : (bih1[jcol] + bhh1[jcol]);

  float lg0 = 0.f, lg1 = 0.f;
  __syncthreads();  // weights staged

  // ---- prologue: prebuf for t=0 ----
  {
    const f4* xq = x4p + (size_t)kq0 * 32 + b;
    f4 xp[16];
    #pragma unroll
    for (int q = 0; q < 16; ++q) ld_x4(xp[q], xq + (size_t)q * 32);
    asm volatile("s_waitcnt vmcnt(0)");
    __builtin_amdgcn_sched_barrier(0xF4);
    f4 p0 = (f4)0.f, p1 = (f4)0.f, p2 = (f4)0.f, p3 = (f4)0.f;
    #pragma unroll
    for (int q = 0; q < 16; ++q) {
      p0 += w4[3072 + 0 * 256 + kq0 + q] * xp[q];
      p1 += w4[3072 + 1 * 256 + kq0 + q] * xp[q];
      p2 += w4[3072 + 2 * 256 + kq0 + q] * xp[q];
      p3 += w4[3072 + 3 * 256 + kq0 + q] * xp[q];
    }
    prebuf[(kg * 4 + 0) * 32 + b] = hsum(p0);
    prebuf[(kg * 4 + 1) * 32 + b] = hsum(p1);
    prebuf[(kg * 4 + 2) * 32 + b] = hsum(p2);
    prebuf[(kg * 4 + 3) * 32 + b] = hsum(p3);
  }

  for (int s = 0; s <= NT; ++s) {
    // ---- one-hop symmetric barrier: 256 lanes poll 256 contiguous flags ----
    if (tid < 256) {
      const unsigned* fp = &flags[tid];
      while (ld_flag(fp) < (unsigned)s) {}
    }
    __syncthreads();
    __builtin_amdgcn_sched_barrier(0);

    const int rp = s & 1;
    const bool l1act = (s >= 1);

    // Wcls prefetch (pinned older than counted h-load batch)
    float wc0 = 0.f, wc1 = 0.f;
    if (tid >= 128 && tid < 256) {
      const int t = l1act ? (s - 1) : 0;
      wc0 = Wcls[(size_t)t * 1024 + jcol];
      wc1 = Wcls[(size_t)524288 + (size_t)t * 1024 + jcol];
    }
    __builtin_amdgcn_sched_barrier(0);

    // ---- batched bf16 h loads: 32+32 dwords (coalesced 128B/wave-row) ----
    const unsigned* pa = hball + (rp ? H01 : H00) + kg * 1024 + b;
    const unsigned* pb = hball + (rp ? H11 : H10) + kg * 1024 + b;
    unsigned ha[32], hb_[32];
    f4 xv[16];
    #pragma unroll
    for (int q = 0; q < 32; ++q) ld_bf(ha[q], pa + q * 32);
    #pragma unroll
    for (int q = 0; q < 32; ++q) ld_bf(hb_[q], pb + q * 32);

    f4 acc[8];
    #pragma unroll
    for (int r = 0; r < 8; ++r) acc[r] = (f4)0.f;

    asm volatile("s_waitcnt vmcnt(48)");      // ha[0..15] done (in-order)
    __builtin_amdgcn_sched_barrier(0xF4);
    #pragma unroll
    for (int i = 0; i < 8; ++i) {
      f4 hf;
      hf[0] = bflo(ha[2*i]);   hf[1] = bfhi(ha[2*i]);
      hf[2] = bflo(ha[2*i+1]); hf[3] = bfhi(ha[2*i+1]);
      #pragma unroll
      for (int r = 0; r < 4; ++r) {
        acc[r]     += w4[r * 256 + kq0 + i] * hf;          // Whh0 -> h0
        acc[4 + r] += w4[1024 + r * 256 + kq0 + i] * hf;   // Wih1 -> h1
      }
    }
    asm volatile("s_waitcnt vmcnt(32)");      // ha[16..31] done
    __builtin_amdgcn_sched_barrier(0xF4);
    #pragma unroll
    for (int i = 8; i < 16; ++i) {
      f4 hf;
      hf[0] = bflo(ha[2*i]);   hf[1] = bfhi(ha[2*i]);
      hf[2] = bflo(ha[2*i+1]); hf[3] = bfhi(ha[2*i+1]);
      #pragma unroll
      for (int r = 0; r < 4; ++r) {
        acc[r]     += w4[r * 256 + kq0 + i] * hf;
        acc[4 + r] += w4[1024 + r * 256 + kq0 + i] * hf;
      }
    }

    // issue next-step x loads (newest 16)
    const int tn = (s + 1 < NT) ? (s + 1) : (NT - 1);
    {
      const f4* xq = x4p + (size_t)tn * 8192 + (size_t)kq0 * 32 + b;
      #pragma unroll
      for (int q = 0; q < 16; ++q) ld_x4(xv[q], xq + (size_t)q * 32);
    }

    asm volatile("s_waitcnt vmcnt(16)");      // hb_ all done (x newest 16)
    __builtin_amdgcn_sched_barrier(0xF4);
    #pragma unroll
    for (int i = 0; i < 16; ++i) {
      f4 hf;
      hf[0] = bflo(hb_[2*i]);   hf[1] = bfhi(hb_[2*i]);
      hf[2] = bflo(hb_[2*i+1]); hf[3] = bfhi(hb_[2*i+1]);
      #pragma unroll
      for (int r = 0; r < 4; ++r)
        acc[4 + r] += w4[2048 + r * 256 + kq0 + i] * hf;   // Whh1 -> h1
    }

    #pragma unroll
    for (int r = 0; r < 8; ++r)
      part[(kg * 8 + r) * 32 + b] = hsum(acc[r]);
    __syncthreads();   // also drains xv loads

    // ---- reduce + tanh ----
    float hv = 0.f;
    if (tid < 256) {
      if (rj < 4) {
        if (s < NT) {
          float sum = bias;
          #pragma unroll
          for (int k = 0; k < 16; ++k) sum += part[(k * 8 + rj) * 32 + b];
          #pragma unroll
          for (int k = 0; k < 16; ++k) sum += prebuf[(k * 4 + rj) * 32 + b];
          hv = tanhf(sum);
          if (s == NT - 1) out[64 + (size_t)b * 1024 + jcol] = hv;
        }
      } else if (l1act) {
        float sum = bias;
        #pragma unroll
        for (int k = 0; k < 16; ++k) sum += part[(k * 8 + 4 + (rj - 4)) * 32 + b];
        hv = tanhf(sum);
        if (s == NT) out[64 + 32768 + (size_t)b * 1024 + jcol] = hv;
      }
    }

    // ---- pack pair via shfl + coherent bf16 store (wave-uniform guards) ----
    float hvp = __shfl_xor(hv, 32);
    if (tid < 256) {
      const bool act = (rj < 4) ? (s < NT) : l1act;
      if (act && ((tid & 63) < 32)) {
        unsigned u = pack_bf16(hv, hvp);
        unsigned* dst = hball + ((rj < 4) ? (rp ? H00 : H01) : (rp ? H10 : H11));
        const int kp = 2 * bid + ((rj >> 1) & 1);
        st_cohu(dst + kp * 32 + b, u);
      }
    }
    __syncthreads();  // drains h stores before flag publish
    if (tid == 0) st_cohu(&flags[bid], (unsigned)(s + 1));

    // ---- off-critical-path: logits FMA + input-projection for t=tn ----
    if (tid >= 128 && tid < 256 && l1act) {
      lg0 = fmaf(hv, wc0, lg0);
      lg1 = fmaf(hv, wc1, lg1);
    }
    {
      f4 p0 = (f4)0.f, p1 = (f4)0.f, p2 = (f4)0.f, p3 = (f4)0.f;
      #pragma unroll
      for (int q = 0; q < 16; ++q) {
        p0 += w4[3072 + 0 * 256 + kq0 + q] * xv[q];
        p1 += w4[3072 + 1 * 256 + kq0 + q] * xv[q];
        p2 += w4[3072 + 2 * 256 + kq0 + q] * xv[q];
        p3 += w4[3072 + 3 * 256 + kq0 + q] * xv[q];
      }
      prebuf[(kg * 4 + 0) * 32 + b] = hsum(p0);
      prebuf[(kg * 4 + 1) * 32 + b] = hsum(p1);
      prebuf[(kg * 4 + 2) * 32 + b] = hsum(p2);
      prebuf[(kg * 4 + 3) * 32 + b] = hsum(p3);
    }
  }

  // ---- epilogue: classifier ----
  if (tid >= 128 && tid < 256) {
    const int r1 = rj - 4;
    part[r1 * 64 + b] = lg0;
    part[r1 * 64 + 32 + b] = lg1;
  }
  __syncthreads();
  if (tid < 64) {
    const int c = tid >> 5, bb = tid & 31;
    float v = 0.f;
    #pragma unroll
    for (int r1 = 0; r1 < 4; ++r1) v += part[r1 * 64 + c * 32 + bb];
    st_cohf(&ws[PLOG + (size_t)bid * 64 + c * 32 + bb], v);
  }
  __syncthreads();  // drain plog stores
  if (tid == 0) st_cohu(&flags[bid], 600u);

  if (bid == 0) {
    if (tid < 256) {
      const unsigned* fp = &flags[tid];
      while (ld_flag(fp) < 600u) {}
    }
    __syncthreads();
    __builtin_amdgcn_sched_barrier(0);
    if (tid < 256) {
      const int g = tid >> 6, pair = tid & 63;
      float v = 0.f;
      for (int blk = g; blk < 256; blk += 4)
        v += __hip_atomic_load(&ws[PLOG + (size_t)blk * 64 + pair],
                               __ATOMIC_RELAXED, __HIP_MEMORY_SCOPE_AGENT);
      part[tid] = v;
    }
    __syncthreads();
    if (tid < 64) {
      float s2 = bcls[tid >> 5];
      #pragma unroll
      for (int g = 0; g < 4; ++g) s2 += part[g * 64 + tid];
      out[(size_t)(tid & 31) * 2 + (tid >> 5)] = s2;  // logits [B,C]
    }
  }
}

extern "C" void kernel_launch(void* const* d_in, const int* in_sizes, int n_in,
                              void* d_out, int out_size, void* d_ws, size_t ws_size,
                              hipStream_t stream) {
  const float* x    = (const float*)d_in[0];
  const float* h0   = (const float*)d_in[1];
  const float* Wih0 = (const float*)d_in[2];
  const float* Whh0 = (const float*)d_in[3];
  const float* bih0 = (const float*)d_in[4];
  const float* bhh0 = (const float*)d_in[5];
  const float* Wih1 = (const float*)d_in[6];
  const float* Whh1 = (const float*)d_in[7];
  const float* bih1 = (const float*)d_in[8];
  const float* bhh1 = (const float*)d_in[9];
  const float* Wcls = (const float*)d_in[10];
  const float* bcls = (const float*)d_in[11];
  float* out = (float*)d_out;
  float* ws  = (float*)d_ws;

  hipFuncSetAttribute((const void*)rnn_kernel,
                      hipFuncAttributeMaxDynamicSharedMemorySize, 90112);

  hipLaunchKernelGGL(init_kernel, dim3(128), dim3(256), 0, stream, h0, ws);
  hipLaunchKernelGGL(xpose_kernel, dim3(512), dim3(256), 0, stream, x, ws);

  void* args[] = { (void*)&bih0, (void*)&bhh0, (void*)&Whh0, (void*)&Wih0,
                   (void*)&Wih1, (void*)&Whh1, (void*)&bih1, (void*)&bhh1,
                   (void*)&Wcls, (void*)&bcls, (void*)&out, (void*)&ws };
  hipLaunchCooperativeKernel((void*)rnn_kernel, dim3(256), dim3(512), args,
                             90112, stream);
}

// Round 9
// 2702.483 us; speedup vs baseline: 2.0381x; 2.0381x over previous
//
#include <hip/hip_runtime.h>
#include <math.h>

typedef float f4 __attribute__((ext_vector_type(4)));
typedef short bf16x8 __attribute__((ext_vector_type(8)));
typedef unsigned u32x2 __attribute__((ext_vector_type(2)));
typedef unsigned u32x4 __attribute__((ext_vector_type(4)));

#define NT 512

// ---- ws dword offsets ----
#define H00 0            // each h buf: hi[4096 f4] + lo[4096 f4] = 32768 dwords
#define H01 32768
#define H10 65536
#define H11 98304
#define PLOG 131072      // 64 blocks * 64 floats
#define FLAGS 135168     // flags[bid*32] (bid<128, 4096 dw) + relc[g*32] (256 dw)
#define WSW  139520      // 4 mat * 2 part * 131072 f4 = 4194304 dwords (16 MB)
#define XBF  4333824     // 512 t * 128 kc * 32 b f4 = 8388608 dwords (32 MB)

__device__ __forceinline__ unsigned pack_bf16(float lo, float hi) {
  unsigned u;
  asm volatile("v_cvt_pk_bf16_f32 %0, %1, %2" : "=v"(u) : "v"(lo), "v"(hi));
  return u;  // low16 = bf16(lo), high16 = bf16(hi), RNE
}
__device__ __forceinline__ float bflo(unsigned d) { return __uint_as_float(d << 16); }
__device__ __forceinline__ float bfhi(unsigned d) { return __uint_as_float(d & 0xffff0000u); }
__device__ __forceinline__ void st_cohf(float* p, float v) {
  __hip_atomic_store(p, v, __ATOMIC_RELAXED, __HIP_MEMORY_SCOPE_AGENT);
}
__device__ __forceinline__ void st_cohu(unsigned* p, unsigned v) {
  __hip_atomic_store(p, v, __ATOMIC_RELAXED, __HIP_MEMORY_SCOPE_AGENT);
}
__device__ __forceinline__ unsigned ld_flag(const unsigned* p) {
  return __hip_atomic_load(p, __ATOMIC_RELAXED, __HIP_MEMORY_SCOPE_AGENT);
}

// split 8 fp32 -> hi/lo packed dwords
__device__ __forceinline__ void split8(const f4 v0, const f4 v1, u32x4& hi, u32x4& lo) {
  float h_[8] = {v0[0], v0[1], v0[2], v0[3], v1[0], v1[1], v1[2], v1[3]};
  #pragma unroll
  for (int e = 0; e < 4; ++e) hi[e] = pack_bf16(h_[2*e], h_[2*e+1]);
  float r[8];
  #pragma unroll
  for (int e = 0; e < 4; ++e) {
    r[2*e]   = h_[2*e]   - bflo(hi[e]);
    r[2*e+1] = h_[2*e+1] - bfhi(hi[e]);
  }
  #pragma unroll
  for (int e = 0; e < 4; ++e) lo[e] = pack_bf16(r[2*e], r[2*e+1]);
}

// W[mat] fp32 row-major -> WSW[(mat*2+part)][kc][...] swizzled bf16 hi/lo
__global__ __launch_bounds__(128) void wconv_kernel(
    const float* __restrict__ W0, const float* __restrict__ W1,
    const float* __restrict__ W2, const float* __restrict__ W3,
    float* __restrict__ ws) {
  const int mat = blockIdx.x >> 10;
  const int j = blockIdx.x & 1023;
  const int kc = threadIdx.x;  // 0..127
  const float* Wm = (mat == 0) ? W0 : (mat == 1) ? W1 : (mat == 2) ? W2 : W3;
  const f4* src = (const f4*)(Wm + (size_t)j * 1024 + kc * 8);
  f4 v0 = src[0], v1 = src[1];
  u32x4 hi, lo;
  split8(v0, v1, hi, lo);
  u32x4* dst = (u32x4*)((f4*)ws + (WSW >> 2));
  size_t base = (size_t)(mat * 2) * 131072 + (j >> 4) * 2048 + kc * 16 + (j & 15);
  dst[base] = hi;
  dst[base + 131072] = lo;
}

// x[b][t][k] fp32 -> XBF[t][kc][b] single-bf16 f4 (8 k per f4)
__global__ __launch_bounds__(128) void xconv_kernel(const float* __restrict__ x,
                                                    float* __restrict__ ws) {
  const int t = blockIdx.x;
  const int kc = threadIdx.x;  // 0..127
  u32x4* dst = (u32x4*)((f4*)ws + (XBF >> 2)) + (size_t)t * 4096;
  for (int b = 0; b < 32; ++b) {
    const f4* src = (const f4*)(x + ((size_t)b * NT + t) * 1024 + kc * 8);
    f4 v0 = src[0], v1 = src[1];
    u32x4 p;
    #pragma unroll
    for (int e = 0; e < 4; ++e)
      p[e] = pack_bf16(e < 2 ? v0[2*e] : v1[2*e-4], e < 2 ? v0[2*e+1] : v1[2*e-3]);
    dst[(size_t)kc * 32 + b] = p;
  }
}

// h0 fp32 [l][b][k] -> split bf16 h bufs; zero flags
__global__ __launch_bounds__(256) void hinit_kernel(const float* __restrict__ h0,
                                                    float* __restrict__ ws) {
  int g = blockIdx.x * 256 + threadIdx.x;  // 0..8191
  int l = g >> 12, b = (g >> 7) & 31, kc = g & 127;
  const f4* src = (const f4*)(h0 + (size_t)l * 32768 + b * 1024 + kc * 8);
  f4 v0 = src[0], v1 = src[1];
  u32x4 hi, lo;
  split8(v0, v1, hi, lo);
  u32x4* d = (u32x4*)((unsigned*)ws + (l ? H11 : H00));
  d[(size_t)kc * 32 + b] = hi;
  d[4096 + (size_t)kc * 32 + b] = lo;
  if (g < 4352) ((unsigned*)ws)[FLAGS + g] = 0u;
}

#define LDG(dst, ptr) \
  asm volatile("global_load_dwordx4 %0, %1, off sc0" : "=v"(dst) : "v"(ptr))
#define MFMA(a, b, c) __builtin_amdgcn_mfma_f32_16x16x32_bf16(a, b, c, 0, 0, 0)
#define BC(v) __builtin_bit_cast(bf16x8, v)

#define KT_L0(kt, N)                                                     \
  asm volatile("s_waitcnt vmcnt(" #N ")");                               \
  __builtin_amdgcn_sched_barrier(0xF4);                                  \
  {                                                                      \
    const int ci = (ch0 + kt * 4) * 16 + jl;                             \
    bf16x8 a0 = w4b[ci], a1 = w4b[2048 + ci], a2 = w4b[4096 + ci];       \
    bf16x8 vh = BC(bh[kt]), vl = BC(bl[kt]), vx = BC(bx[kt]);            \
    cr = MFMA(a0, vh, cr); cr = MFMA(a0, vl, cr); cr = MFMA(a1, vh, cr); \
    cp = MFMA(a2, vx, cp);                                               \
  }

#define KT_L1(kt, N)                                                     \
  asm volatile("s_waitcnt vmcnt(" #N ")");                               \
  __builtin_amdgcn_sched_barrier(0xF4);                                  \
  {                                                                      \
    const int ci = (ch0 + kt * 4) * 16 + jl;                             \
    bf16x8 a0 = w4b[ci], a1 = w4b[2048 + ci];                            \
    bf16x8 a2 = w4b[4096 + ci], a3 = w4b[6144 + ci];                     \
    bf16x8 h0h = BC(bh[kt]), h0l = BC(bl[kt]);                           \
    bf16x8 h1h = BC(ch_[kt]), h1l = BC(cl_[kt]);                         \
    cr = MFMA(a0, h0h, cr); cr = MFMA(a0, h0l, cr); cr = MFMA(a1, h0h, cr); \
    cr = MFMA(a2, h1h, cr); cr = MFMA(a2, h1l, cr); cr = MFMA(a3, h1h, cr); \
  }

#define KT_PRE(kt, N)                                                    \
  asm volatile("s_waitcnt vmcnt(" #N ")");                               \
  __builtin_amdgcn_sched_barrier(0xF4);                                  \
  {                                                                      \
    const int ci = (ch0 + kt * 4) * 16 + jl;                             \
    bf16x8 a2 = w4b[4096 + ci];                                          \
    cp = MFMA(a2, BC(bx[kt]), cp);                                       \
  }

// 128 blocks x 512 threads. Block bid<64: L0 {Whh0, Wih0}; bid>=64: L1 {Wih1, Whh1}.
// Each block owns j-slice (bid&63)*16, full K=1024 (no cross-block reduction).
__global__ __launch_bounds__(512, 1) void rnn_kernel(
    const float* __restrict__ bih0, const float* __restrict__ bhh0,
    const float* __restrict__ bih1, const float* __restrict__ bhh1,
    const float* __restrict__ Wcls, const float* __restrict__ bcls,
    float* __restrict__ out, float* ws) {
  extern __shared__ float smem[];
  f4* w4 = (f4*)smem;                       // 8192 f4 = 128 KB (4 slots x 2048)
  bf16x8* w4b = (bf16x8*)smem;
  f4* partR = w4 + 8192;                    // 512 f4 (8 KB)
  f4* partP = w4 + 8704;                    // 512 f4 (8 KB)
  float* prebuf = smem + 36864;             // [2][16][32] f32 (4 KB)

  const int bid = blockIdx.x, tid = threadIdx.x;
  const bool isL1 = bid >= 64;
  const int jsl = bid & 63;
  const int l = tid & 63, w = tid >> 6;
  const int nt = w & 1, ks = w >> 1;        // N-tile, K-slice
  const int jl = l & 15;
  const int bcol = nt * 16 + (l & 15);
  const int ch0 = ks * 32 + (l >> 4);       // base k-chunk for this lane

  unsigned* flags = (unsigned*)ws + FLAGS;
  unsigned* relc = flags + 4096;
  const f4* wsf4 = (const f4*)ws;

  // ---- stage 4 weight slots (this block's 16 rows, bf16 hi/lo swizzled) ----
  {
    const int m0 = isL1 ? 2 : 0;
    for (int i = tid; i < 8192; i += 512) {
      const int slot = i >> 11, idx = i & 2047;
      const int mat = m0 + (slot >> 1), part = slot & 1;
      w4[i] = wsf4[(WSW >> 2) + (size_t)(mat * 2 + part) * 131072 +
                   jsl * 2048 + idx];
    }
  }

  // reducer constants (tid<128): lane -> (b, 4 j's)
  const int rr = tid & 63, ntr = (tid >> 6) & 1;
  const int b_r = ntr * 16 + (rr & 15);
  const int jg = rr >> 4;
  const int jcol0 = jsl * 16 + jg * 4;
  f4 biasv = (f4)0.f;
  if (tid < 128) {
    f4 bi = isL1 ? *(const f4*)(bih1 + jcol0) : *(const f4*)(bih0 + jcol0);
    f4 bh2 = isL1 ? *(const f4*)(bhh1 + jcol0) : *(const f4*)(bhh0 + jcol0);
    biasv = bi + bh2;
  }
  float lg0 = 0.f, lg1 = 0.f;
  __syncthreads();  // weights staged

  // ---- prologue (L0): prebuf[0] = x_0 . Wih0_hi ----
  if (!isL1) {
    f4 bx[8];
    const f4* px = wsf4 + (XBF >> 2) + ch0 * 32 + bcol;  // t=0
    LDG(bx[0], px);            LDG(bx[1], px + 128);
    LDG(bx[2], px + 256);      LDG(bx[3], px + 384);
    LDG(bx[4], px + 512);      LDG(bx[5], px + 640);
    LDG(bx[6], px + 768);      LDG(bx[7], px + 896);
    f4 cp = (f4)0.f;
    KT_PRE(0, 7) KT_PRE(1, 6) KT_PRE(2, 5) KT_PRE(3, 4)
    KT_PRE(4, 3) KT_PRE(5, 2) KT_PRE(6, 1) KT_PRE(7, 0)
    partP[(ks * 2 + nt) * 64 + l] = cp;
    __syncthreads();
    if (tid >= 128 && tid < 256) {
      f4 sum = partP[ntr * 64 + rr] + partP[(2 + ntr) * 64 + rr] +
               partP[(4 + ntr) * 64 + rr] + partP[(6 + ntr) * 64 + rr];
      #pragma unroll
      for (int e = 0; e < 4; ++e)
        prebuf[(jg * 4 + e) * 32 + b_r] = sum[e];
    }
    __syncthreads();
  }

  for (int s = 0; s <= NT; ++s) {
    // ---- grid barrier (R7-proven relay; per-block private flag lines) ----
    if (bid == 0) {
      if (tid < 128) {
        const unsigned* fp = &flags[tid * 32];
        while (ld_flag(fp) < (unsigned)s) {}
      }
      __syncthreads();
      if (tid < 8) st_cohu(&relc[tid * 32], (unsigned)s);
    } else {
      if (tid == 0) {
        const unsigned* rxp = &relc[(bid & 7) * 32];
        while (ld_flag(rxp) < (unsigned)s) {}
      }
      __syncthreads();
    }
    __builtin_amdgcn_sched_barrier(0);

    const int rp = s & 1;
    const bool act = isL1 ? (s >= 1) : (s < NT);

    // Wcls prefetch (extra VMEM only makes vmcnt counting conservative)
    f4 wc0 = (f4)0.f, wc1 = (f4)0.f;
    if (isL1 && tid < 128 && s >= 1) {
      wc0 = *(const f4*)(Wcls + (size_t)(s - 1) * 1024 + jcol0);
      wc1 = *(const f4*)(Wcls + (size_t)524288 + (size_t)(s - 1) * 1024 + jcol0);
    }

    if (act) {
      if (!isL1) {
        const int tn = (s + 1 < NT) ? (s + 1) : (NT - 1);
        const f4* ph = wsf4 + ((rp ? H01 : H00) >> 2) + ch0 * 32 + bcol;
        const f4* pl = ph + 4096;
        const f4* px = wsf4 + (XBF >> 2) + (size_t)tn * 4096 + ch0 * 32 + bcol;
        f4 bh[8], bl[8], bx[8];
        LDG(bh[0], ph);       LDG(bl[0], pl);       LDG(bx[0], px);
        LDG(bh[1], ph + 128); LDG(bl[1], pl + 128); LDG(bx[1], px + 128);
        LDG(bh[2], ph + 256); LDG(bl[2], pl + 256); LDG(bx[2], px + 256);
        LDG(bh[3], ph + 384); LDG(bl[3], pl + 384); LDG(bx[3], px + 384);
        LDG(bh[4], ph + 512); LDG(bl[4], pl + 512); LDG(bx[4], px + 512);
        LDG(bh[5], ph + 640); LDG(bl[5], pl + 640); LDG(bx[5], px + 640);
        LDG(bh[6], ph + 768); LDG(bl[6], pl + 768); LDG(bx[6], px + 768);
        LDG(bh[7], ph + 896); LDG(bl[7], pl + 896); LDG(bx[7], px + 896);
        f4 cr = (f4)0.f, cp = (f4)0.f;
        KT_L0(0, 21) KT_L0(1, 18) KT_L0(2, 15) KT_L0(3, 12)
        KT_L0(4, 9)  KT_L0(5, 6)  KT_L0(6, 3)  KT_L0(7, 0)
        partR[(ks * 2 + nt) * 64 + l] = cr;
        partP[(ks * 2 + nt) * 64 + l] = cp;
      } else {
        const f4* ph = wsf4 + ((rp ? H01 : H00) >> 2) + ch0 * 32 + bcol;
        const f4* pl = ph + 4096;
        const f4* qh = wsf4 + ((rp ? H11 : H10) >> 2) + ch0 * 32 + bcol;
        const f4* ql = qh + 4096;
        f4 bh[8], bl[8], ch_[8], cl_[8];
        LDG(bh[0], ph);       LDG(bl[0], pl);       LDG(ch_[0], qh);       LDG(cl_[0], ql);
        LDG(bh[1], ph + 128); LDG(bl[1], pl + 128); LDG(ch_[1], qh + 128); LDG(cl_[1], ql + 128);
        LDG(bh[2], ph + 256); LDG(bl[2], pl + 256); LDG(ch_[2], qh + 256); LDG(cl_[2], ql + 256);
        LDG(bh[3], ph + 384); LDG(bl[3], pl + 384); LDG(ch_[3], qh + 384); LDG(cl_[3], ql + 384);
        LDG(bh[4], ph + 512); LDG(bl[4], pl + 512); LDG(ch_[4], qh + 512); LDG(cl_[4], ql + 512);
        LDG(bh[5], ph + 640); LDG(bl[5], pl + 640); LDG(ch_[5], qh + 640); LDG(cl_[5], ql + 640);
        LDG(bh[6], ph + 768); LDG(bl[6], pl + 768); LDG(ch_[6], qh + 768); LDG(cl_[6], ql + 768);
        LDG(bh[7], ph + 896); LDG(bl[7], pl + 896); LDG(ch_[7], qh + 896); LDG(cl_[7], ql + 896);
        f4 cr = (f4)0.f;
        KT_L1(0, 28) KT_L1(1, 24) KT_L1(2, 20) KT_L1(3, 16)
        KT_L1(4, 12) KT_L1(5, 8)  KT_L1(6, 4)  KT_L1(7, 0)
        partR[(ks * 2 + nt) * 64 + l] = cr;
      }
      __syncthreads();

      // ---- reduce + tanh + split-bf16 store ----
      if (tid < 128) {
        f4 sum = partR[ntr * 64 + rr] + partR[(2 + ntr) * 64 + rr] +
                 partR[(4 + ntr) * 64 + rr] + partR[(6 + ntr) * 64 + rr];
        float h_[4];
        #pragma unroll
        for (int e = 0; e < 4; ++e) {
          float v = sum[e] + biasv[e];
          if (!isL1) v += prebuf[rp * 512 + (jg * 4 + e) * 32 + b_r];
          h_[e] = tanhf(v);
        }
        unsigned hi0 = pack_bf16(h_[0], h_[1]), hi1 = pack_bf16(h_[2], h_[3]);
        float r0 = h_[0] - bflo(hi0), r1 = h_[1] - bfhi(hi0);
        float r2 = h_[2] - bflo(hi1), r3 = h_[3] - bfhi(hi1);
        unsigned lo0 = pack_bf16(r0, r1), lo1 = pack_bf16(r2, r3);
        u32x2 hp; hp[0] = hi0; hp[1] = hi1;
        u32x2 lp; lp[0] = lo0; lp[1] = lo1;
        unsigned dstb = isL1 ? (rp ? H10 : H11) : (rp ? H00 : H01);
        unsigned* dp = (unsigned*)ws + dstb + ((jcol0 >> 3) * 32 + b_r) * 4 +
                       ((jcol0 >> 1) & 3);
        asm volatile("global_store_dwordx2 %0, %1, off sc0 sc1" ::"v"(dp), "v"(hp) : "memory");
        asm volatile("global_store_dwordx2 %0, %1, off sc0 sc1" ::"v"(dp + 16384), "v"(lp) : "memory");
        if (isL1) {
          lg0 += h_[0]*wc0[0] + h_[1]*wc0[1] + h_[2]*wc0[2] + h_[3]*wc0[3];
          lg1 += h_[0]*wc1[0] + h_[1]*wc1[1] + h_[2]*wc1[2] + h_[3]*wc1[3];
          if (s == NT) {
            f4 o; o[0]=h_[0]; o[1]=h_[1]; o[2]=h_[2]; o[3]=h_[3];
            *(f4*)(out + 64 + 32768 + (size_t)b_r * 1024 + jcol0) = o;
          }
        } else if (s == NT - 1) {
          f4 o; o[0]=h_[0]; o[1]=h_[1]; o[2]=h_[2]; o[3]=h_[3];
          *(f4*)(out + 64 + (size_t)b_r * 1024 + jcol0) = o;
        }
      } else if (tid < 256 && !isL1) {
        // pre-reduce for t = s+1 -> prebuf[rp^1]
        f4 sum = partP[ntr * 64 + rr] + partP[(2 + ntr) * 64 + rr] +
                 partP[(4 + ntr) * 64 + rr] + partP[(6 + ntr) * 64 + rr];
        #pragma unroll
        for (int e = 0; e < 4; ++e)
          prebuf[(rp ^ 1) * 512 + (jg * 4 + e) * 32 + b_r] = sum[e];
      }
    }
    asm volatile("s_waitcnt vmcnt(0)");  // drain asm h stores
    __syncthreads();
    if (tid == 0) st_cohu(&flags[bid * 32], (unsigned)(s + 1));
  }

  // ---- epilogue: classifier ----
  if (isL1) {
    float* lgred = smem + 36864;  // reuse prebuf region (L1 never used it)
    if (tid < 128) {
      lgred[jg * 32 + b_r] = lg0;
      lgred[128 + jg * 32 + b_r] = lg1;
    }
    __syncthreads();
    if (tid < 64) {
      const int c = tid >> 5, bb = tid & 31;
      float v = 0.f;
      #pragma unroll
      for (int g2 = 0; g2 < 4; ++g2) v += lgred[c * 128 + g2 * 32 + bb];
      st_cohf(&ws[PLOG + (size_t)(bid - 64) * 64 + c * 32 + bb], v);
    }
    __syncthreads();  // drains plog store
    if (tid == 0) st_cohu(&flags[bid * 32], 600u);
  } else if (bid == 0) {
    if (tid < 64) {
      const unsigned* fp = &flags[(64 + tid) * 32];
      while (ld_flag(fp) < 600u) {}
    }
    __syncthreads();
    __builtin_amdgcn_sched_barrier(0);
    float* lgred = smem + 36864;
    if (tid < 256) {
      const int g2 = tid >> 6, pair = tid & 63;
      float v = 0.f;
      for (int blk = g2; blk < 64; blk += 4)
        v += __hip_atomic_load(&ws[PLOG + (size_t)blk * 64 + pair],
                               __ATOMIC_RELAXED, __HIP_MEMORY_SCOPE_AGENT);
      lgred[tid] = v;
    }
    __syncthreads();
    if (tid < 64) {
      float s2 = bcls[tid >> 5];
      #pragma unroll
      for (int g2 = 0; g2 < 4; ++g2) s2 += lgred[g2 * 64 + tid];
      out[(size_t)(tid & 31) * 2 + (tid >> 5)] = s2;  // logits [B,C]
    }
  }
}

extern "C" void kernel_launch(void* const* d_in, const int* in_sizes, int n_in,
                              void* d_out, int out_size, void* d_ws, size_t ws_size,
                              hipStream_t stream) {
  const float* x    = (const float*)d_in[0];
  const float* h0   = (const float*)d_in[1];
  const float* Wih0 = (const float*)d_in[2];
  const float* Whh0 = (const float*)d_in[3];
  const float* bih0 = (const float*)d_in[4];
  const float* bhh0 = (const float*)d_in[5];
  const float* Wih1 = (const float*)d_in[6];
  const float* Whh1 = (const float*)d_in[7];
  const float* bih1 = (const float*)d_in[8];
  const float* bhh1 = (const float*)d_in[9];
  const float* Wcls = (const float*)d_in[10];
  const float* bcls = (const float*)d_in[11];
  float* out = (float*)d_out;
  float* ws  = (float*)d_ws;

  hipFuncSetAttribute((const void*)rnn_kernel,
                      hipFuncAttributeMaxDynamicSharedMemorySize, 151552);

  // mat order: 0=Whh0, 1=Wih0, 2=Wih1, 3=Whh1
  hipLaunchKernelGGL(wconv_kernel, dim3(4096), dim3(128), 0, stream,
                     Whh0, Wih0, Wih1, Whh1, ws);
  hipLaunchKernelGGL(xconv_kernel, dim3(512), dim3(128), 0, stream, x, ws);
  hipLaunchKernelGGL(hinit_kernel, dim3(32), dim3(256), 0, stream, h0, ws);

  void* args[] = { (void*)&bih0, (void*)&bhh0, (void*)&bih1, (void*)&bhh1,
                   (void*)&Wcls, (void*)&bcls, (void*)&out, (void*)&ws };
  hipLaunchCooperativeKernel((void*)rnn_kernel, dim3(128), dim3(512), args,
                             151552, stream);
}

// Round 10
// 2416.923 us; speedup vs baseline: 2.2789x; 1.1182x over previous
//
#include <hip/hip_runtime.h>
#include <math.h>

typedef float f4 __attribute__((ext_vector_type(4)));
typedef short bf16x8 __attribute__((ext_vector_type(8)));
typedef unsigned u32x2 __attribute__((ext_vector_type(2)));
typedef unsigned u32x4 __attribute__((ext_vector_type(4)));

#define NT 512

// ---- ws dword offsets ----
#define H0R 0            // 4 ring slots x (hi 4096 f4 + lo 4096 f4) = 131072 dw
#define H1R 131072       // 2 slots x 32768 dw
#define PLOG 196608      // 64*64 floats
#define FLAGS 200704     // 128 flags at stride 32 dw (flag0[64], flag1[64])
#define WSW 204800       // 8 regions x 131072 f4 (16 MB)
#define XBF 4399104      // 512 t x 128 kc x 32 b f4 (32 MB)

__device__ __forceinline__ unsigned pack_bf16(float lo, float hi) {
  unsigned u;
  asm volatile("v_cvt_pk_bf16_f32 %0, %1, %2" : "=v"(u) : "v"(lo), "v"(hi));
  return u;
}
__device__ __forceinline__ float bflo(unsigned d) { return __uint_as_float(d << 16); }
__device__ __forceinline__ float bfhi(unsigned d) { return __uint_as_float(d & 0xffff0000u); }
__device__ __forceinline__ void st_cohf(float* p, float v) {
  __hip_atomic_store(p, v, __ATOMIC_RELAXED, __HIP_MEMORY_SCOPE_AGENT);
}
__device__ __forceinline__ void st_cohu(unsigned* p, unsigned v) {
  __hip_atomic_store(p, v, __ATOMIC_RELAXED, __HIP_MEMORY_SCOPE_AGENT);
}
__device__ __forceinline__ int ld_flag(const unsigned* p) {
  return (int)__hip_atomic_load(p, __ATOMIC_RELAXED, __HIP_MEMORY_SCOPE_AGENT);
}

__device__ __forceinline__ void split8(const f4 v0, const f4 v1, u32x4& hi, u32x4& lo) {
  float h_[8] = {v0[0], v0[1], v0[2], v0[3], v1[0], v1[1], v1[2], v1[3]};
  #pragma unroll
  for (int e = 0; e < 4; ++e) hi[e] = pack_bf16(h_[2*e], h_[2*e+1]);
  float r[8];
  #pragma unroll
  for (int e = 0; e < 4; ++e) {
    r[2*e]   = h_[2*e]   - bflo(hi[e]);
    r[2*e+1] = h_[2*e+1] - bfhi(hi[e]);
  }
  #pragma unroll
  for (int e = 0; e < 4; ++e) lo[e] = pack_bf16(r[2*e], r[2*e+1]);
}

// W fp32 row-major -> WSW[(mat*2+part)] swizzled bf16 hi/lo
// mat order: 0=Whh0, 1=Wih0, 2=Wih1, 3=Whh1
__global__ __launch_bounds__(128) void wconv_kernel(
    const float* __restrict__ W0, const float* __restrict__ W1,
    const float* __restrict__ W2, const float* __restrict__ W3,
    float* __restrict__ ws) {
  const int mat = blockIdx.x >> 10;
  const int j = blockIdx.x & 1023;
  const int kc = threadIdx.x;
  const float* Wm = (mat == 0) ? W0 : (mat == 1) ? W1 : (mat == 2) ? W2 : W3;
  const f4* src = (const f4*)(Wm + (size_t)j * 1024 + kc * 8);
  f4 v0 = src[0], v1 = src[1];
  u32x4 hi, lo;
  split8(v0, v1, hi, lo);
  u32x4* dst = (u32x4*)((f4*)ws + (WSW >> 2));
  size_t base = (size_t)(mat * 2) * 131072 + (j >> 4) * 2048 + kc * 16 + (j & 15);
  dst[base] = hi;
  dst[base + 131072] = lo;
}

// x[b][t][k] fp32 -> XBF[t][kc][b] single-bf16
__global__ __launch_bounds__(128) void xconv_kernel(const float* __restrict__ x,
                                                    float* __restrict__ ws) {
  const int t = blockIdx.x;
  const int kc = threadIdx.x;
  u32x4* dst = (u32x4*)((f4*)ws + (XBF >> 2)) + (size_t)t * 4096;
  for (int b = 0; b < 32; ++b) {
    const f4* src = (const f4*)(x + ((size_t)b * NT + t) * 1024 + kc * 8);
    f4 v0 = src[0], v1 = src[1];
    u32x4 p;
    #pragma unroll
    for (int e = 0; e < 4; ++e)
      p[e] = pack_bf16(e < 2 ? v0[2*e] : v1[2*e-4], e < 2 ? v0[2*e+1] : v1[2*e-3]);
    dst[(size_t)kc * 32 + b] = p;
  }
}

// h0 init: layer0 -> H0R ring slot 3 (h0(-1)); layer1 -> H1R slot 1 (h1(-1))
__global__ __launch_bounds__(256) void hinit_kernel(const float* __restrict__ h0,
                                                    float* __restrict__ ws) {
  int g = blockIdx.x * 256 + threadIdx.x;  // 0..8191
  int l = g >> 12, b = (g >> 7) & 31, kc = g & 127;
  const f4* src = (const f4*)(h0 + (size_t)l * 32768 + b * 1024 + kc * 8);
  f4 v0 = src[0], v1 = src[1];
  u32x4 hi, lo;
  split8(v0, v1, hi, lo);
  unsigned base = l ? (H1R + 32768) : (H0R + 3 * 32768);
  u32x4* d = (u32x4*)((unsigned*)ws + base);
  d[(size_t)kc * 32 + b] = hi;
  d[4096 + (size_t)kc * 32 + b] = lo;
  if (g < 4096) ((unsigned*)ws)[FLAGS + g] = 0u;
}

#define LDG(dst, ptr) \
  asm volatile("global_load_dwordx4 %0, %1, off sc0" : "=v"(dst) : "v"(ptr))
#define MFMA(a, b, c) __builtin_amdgcn_mfma_f32_16x16x32_bf16(a, b, c, 0, 0, 0)
#define BC(v) __builtin_bit_cast(bf16x8, v)

// main: 3 MFMAs on (a0=W_hi, a1=W_lo) x (bh=h_hi, bl=h_lo)
#define KT_M(kt, N)                                                       \
  asm volatile("s_waitcnt vmcnt(" #N ")");                                \
  __builtin_amdgcn_sched_barrier(0xF4);                                   \
  {                                                                       \
    const int ci = (ch0 + kt * 4) * 16 + jl;                              \
    bf16x8 a0 = w4b[ci], a1 = w4b[2048 + ci];                             \
    bf16x8 vh = BC(bh[kt]), vl = BC(bl[kt]);                              \
    cr = MFMA(a0, vh, cr); cr = MFMA(a0, vl, cr); cr = MFMA(a1, vh, cr);  \
  }

// tail (L1): Wih1 x h0, 3 MFMAs
#define KT_G(kt, N)                                                       \
  asm volatile("s_waitcnt vmcnt(" #N ")");                                \
  __builtin_amdgcn_sched_barrier(0xF4);                                   \
  {                                                                       \
    const int ci = (ch0 + kt * 4) * 16 + jl;                              \
    bf16x8 a2 = w4b[4096 + ci], a3 = w4b[6144 + ci];                      \
    bf16x8 vh = BC(gh[kt]), vl = BC(gl[kt]);                              \
    cp = MFMA(a2, vh, cp); cp = MFMA(a2, vl, cp); cp = MFMA(a3, vh, cp);  \
  }

// tail (L0): Wih0_hi x x, 1 MFMA
#define KT_X(kt, N)                                                       \
  asm volatile("s_waitcnt vmcnt(" #N ")");                                \
  __builtin_amdgcn_sched_barrier(0xF4);                                   \
  {                                                                       \
    const int ci = (ch0 + kt * 4) * 16 + jl;                              \
    bf16x8 a2 = w4b[4096 + ci];                                           \
    cp = MFMA(a2, BC(bx[kt]), cp);                                        \
  }

#define LD16(A, B, pa, pb)                                                \
  LDG(A[0], pa);       LDG(B[0], pb);                                     \
  LDG(A[1], pa + 128); LDG(B[1], pb + 128);                               \
  LDG(A[2], pa + 256); LDG(B[2], pb + 256);                               \
  LDG(A[3], pa + 384); LDG(B[3], pb + 384);                               \
  LDG(A[4], pa + 512); LDG(B[4], pb + 512);                               \
  LDG(A[5], pa + 640); LDG(B[5], pb + 640);                               \
  LDG(A[6], pa + 768); LDG(B[6], pb + 768);                               \
  LDG(A[7], pa + 896); LDG(B[7], pb + 896);

// 128 blocks x 512 threads. bid<64: L0 group {Whh0, Wih0}; bid>=64: L1 {Whh1, Wih1}.
__global__ __launch_bounds__(512, 1) void rnn_kernel(
    const float* __restrict__ bih0, const float* __restrict__ bhh0,
    const float* __restrict__ bih1, const float* __restrict__ bhh1,
    const float* __restrict__ Wcls, const float* __restrict__ bcls,
    float* __restrict__ out, float* ws) {
  extern __shared__ float smem[];
  f4* w4 = (f4*)smem;                       // 8192 f4 = 128 KB (4 slots x 2048)
  bf16x8* w4b = (bf16x8*)smem;
  f4* partR = w4 + 8192;                    // 512 f4
  f4* partP = w4 + 8704;                    // 512 f4
  float* prebuf = smem + 36864;             // [2][16][32] f32

  const int bid = blockIdx.x, tid = threadIdx.x;
  const bool isL1 = bid >= 64;
  const int jsl = bid & 63;
  const int l = tid & 63, w = tid >> 6;
  const int nt = w & 1, ks = w >> 1;
  const int jl = l & 15;
  const int bcol = nt * 16 + (l & 15);
  const int ch0 = ks * 32 + (l >> 4);

  unsigned* flag0 = (unsigned*)ws + FLAGS;         // [64] stride 32
  unsigned* flag1 = flag0 + 64 * 32;               // [64] stride 32
  const f4* wsf4 = (const f4*)ws;

  // ---- stage weights: L0 slots {Whh0_hi, Whh0_lo, Wih0_hi};
  //                     L1 slots {Whh1_hi, Whh1_lo, Wih1_hi, Wih1_lo} ----
  {
    const int nent = isL1 ? 8192 : 6144;
    for (int i = tid; i < nent; i += 512) {
      const int slot = i >> 11, idx = i & 2047;
      const int region = isL1 ? (slot < 2 ? 6 + slot : 2 + slot) : slot;
      w4[i] = wsf4[(WSW >> 2) + (size_t)region * 131072 + jsl * 2048 + idx];
    }
  }

  const int rr = tid & 63, ntr = (tid >> 6) & 1;
  const int b_r = ntr * 16 + (rr & 15);
  const int jg = rr >> 4;
  const int jcol0 = jsl * 16 + jg * 4;
  f4 biasv = (f4)0.f;
  if (tid < 128) {
    f4 bi = isL1 ? *(const f4*)(bih1 + jcol0) : *(const f4*)(bih0 + jcol0);
    f4 bh2 = isL1 ? *(const f4*)(bhh1 + jcol0) : *(const f4*)(bhh0 + jcol0);
    biasv = bi + bh2;
  }
  float lg0 = 0.f, lg1 = 0.f;
  __syncthreads();  // weights staged

  // ---- prologue: prebuf[0] ----
  if (!isL1) {
    f4 bx[8];
    const f4* px = wsf4 + (XBF >> 2) + ch0 * 32 + bcol;  // t=0
    LDG(bx[0], px);       LDG(bx[1], px + 128);
    LDG(bx[2], px + 256); LDG(bx[3], px + 384);
    LDG(bx[4], px + 512); LDG(bx[5], px + 640);
    LDG(bx[6], px + 768); LDG(bx[7], px + 896);
    f4 cp = (f4)0.f;
    KT_X(0, 7) KT_X(1, 6) KT_X(2, 5) KT_X(3, 4)
    KT_X(4, 3) KT_X(5, 2) KT_X(6, 1) KT_X(7, 0)
    partP[(ks * 2 + nt) * 64 + l] = cp;
  } else {
    if (tid < 64) { while (ld_flag(&flag0[tid * 32]) < 1) {} }
    __syncthreads();
    __builtin_amdgcn_sched_barrier(0);
    const f4* gph = wsf4 + (H0R >> 2) + ch0 * 32 + bcol;  // h0(0) = ring slot 0
    const f4* gpl = gph + 4096;
    f4 gh[8], gl[8];
    LD16(gh, gl, gph, gpl)
    f4 cp = (f4)0.f;
    KT_G(0, 14) KT_G(1, 12) KT_G(2, 10) KT_G(3, 8)
    KT_G(4, 6)  KT_G(5, 4)  KT_G(6, 2)  KT_G(7, 0)
    partP[(ks * 2 + nt) * 64 + l] = cp;
  }
  __syncthreads();
  if (tid >= 128 && tid < 256) {
    f4 sum = partP[ntr * 64 + rr] + partP[(2 + ntr) * 64 + rr] +
             partP[(4 + ntr) * 64 + rr] + partP[(6 + ntr) * 64 + rr];
    #pragma unroll
    for (int e = 0; e < 4; ++e) prebuf[(jg * 4 + e) * 32 + b_r] = sum[e];
  }

  if (!isL1) {
    // ======================= L0 group =======================
    for (int s = 0; s < NT; ++s) {
      if (tid < 64) { while (ld_flag(&flag0[tid * 32]) < s) {} }
      else if (tid < 128) {
        const int bound = s - 3;
        while (ld_flag(&flag1[(tid - 64) * 32]) < bound) {}
      }
      __syncthreads();
      __builtin_amdgcn_sched_barrier(0);
      const int pp = s & 1;

      const f4* ph = wsf4 + (H0R >> 2) + ((s + 3) & 3) * 8192 + ch0 * 32 + bcol;
      const f4* pl = ph + 4096;
      f4 bh[8], bl[8];
      LD16(bh, bl, ph, pl)
      f4 cr = (f4)0.f;
      KT_M(0, 14) KT_M(1, 12) KT_M(2, 10) KT_M(3, 8)
      KT_M(4, 6)  KT_M(5, 4)  KT_M(6, 2)  KT_M(7, 0)
      partR[(ks * 2 + nt) * 64 + l] = cr;
      __syncthreads();

      if (tid < 128) {
        f4 sum = partR[ntr * 64 + rr] + partR[(2 + ntr) * 64 + rr] +
                 partR[(4 + ntr) * 64 + rr] + partR[(6 + ntr) * 64 + rr];
        float h_[4];
        #pragma unroll
        for (int e = 0; e < 4; ++e)
          h_[e] = tanhf(sum[e] + biasv[e] + prebuf[pp * 512 + (jg * 4 + e) * 32 + b_r]);
        unsigned hi0 = pack_bf16(h_[0], h_[1]), hi1 = pack_bf16(h_[2], h_[3]);
        unsigned lo0 = pack_bf16(h_[0] - bflo(hi0), h_[1] - bfhi(hi0));
        unsigned lo1 = pack_bf16(h_[2] - bflo(hi1), h_[3] - bfhi(hi1));
        u32x2 hp; hp[0] = hi0; hp[1] = hi1;
        u32x2 lp; lp[0] = lo0; lp[1] = lo1;
        unsigned* dp = (unsigned*)ws + H0R + (s & 3) * 32768 +
                       ((jcol0 >> 3) * 32 + b_r) * 4 + ((jcol0 >> 1) & 3);
        asm volatile("global_store_dwordx2 %0, %1, off sc0 sc1" ::"v"(dp), "v"(hp) : "memory");
        asm volatile("global_store_dwordx2 %0, %1, off sc0 sc1" ::"v"(dp + 16384), "v"(lp) : "memory");
        if (s == NT - 1) {
          f4 o; o[0]=h_[0]; o[1]=h_[1]; o[2]=h_[2]; o[3]=h_[3];
          *(f4*)(out + 64 + (size_t)b_r * 1024 + jcol0) = o;
        }
      }
      asm volatile("s_waitcnt vmcnt(0)");
      __syncthreads();
      if (tid == 0) st_cohu(&flag0[bid * 32], (unsigned)(s + 1));

      if (s < NT - 1) {  // tail: Wih0 x x(s+1) -> prebuf[pp^1]
        const f4* px = wsf4 + (XBF >> 2) + (size_t)(s + 1) * 4096 + ch0 * 32 + bcol;
        f4 bx[8];
        LDG(bx[0], px);       LDG(bx[1], px + 128);
        LDG(bx[2], px + 256); LDG(bx[3], px + 384);
        LDG(bx[4], px + 512); LDG(bx[5], px + 640);
        LDG(bx[6], px + 768); LDG(bx[7], px + 896);
        f4 cp = (f4)0.f;
        KT_X(0, 7) KT_X(1, 6) KT_X(2, 5) KT_X(3, 4)
        KT_X(4, 3) KT_X(5, 2) KT_X(6, 1) KT_X(7, 0)
        partP[(ks * 2 + nt) * 64 + l] = cp;
        __syncthreads();
        if (tid >= 128 && tid < 256) {
          f4 sum = partP[ntr * 64 + rr] + partP[(2 + ntr) * 64 + rr] +
                   partP[(4 + ntr) * 64 + rr] + partP[(6 + ntr) * 64 + rr];
          #pragma unroll
          for (int e = 0; e < 4; ++e)
            prebuf[(pp ^ 1) * 512 + (jg * 4 + e) * 32 + b_r] = sum[e];
        }
      }
    }
  } else {
    // ======================= L1 group =======================
    for (int t = 0; t < NT; ++t) {
      if (tid < 64) { while (ld_flag(&flag1[tid * 32]) < t) {} }
      __syncthreads();
      __builtin_amdgcn_sched_barrier(0);
      const int pp = t & 1;

      f4 wc0 = (f4)0.f, wc1 = (f4)0.f;
      if (tid < 128) {
        wc0 = *(const f4*)(Wcls + (size_t)t * 1024 + jcol0);
        wc1 = *(const f4*)(Wcls + (size_t)524288 + (size_t)t * 1024 + jcol0);
      }
      __builtin_amdgcn_sched_barrier(0);

      const f4* ph = wsf4 + (H1R >> 2) + ((t + 1) & 1) * 8192 + ch0 * 32 + bcol;
      const f4* pl = ph + 4096;
      f4 bh[8], bl[8];
      LD16(bh, bl, ph, pl)
      f4 cr = (f4)0.f;
      KT_M(0, 14) KT_M(1, 12) KT_M(2, 10) KT_M(3, 8)
      KT_M(4, 6)  KT_M(5, 4)  KT_M(6, 2)  KT_M(7, 0)
      partR[(ks * 2 + nt) * 64 + l] = cr;
      __syncthreads();

      if (tid < 128) {
        f4 sum = partR[ntr * 64 + rr] + partR[(2 + ntr) * 64 + rr] +
                 partR[(4 + ntr) * 64 + rr] + partR[(6 + ntr) * 64 + rr];
        float h_[4];
        #pragma unroll
        for (int e = 0; e < 4; ++e)
          h_[e] = tanhf(sum[e] + biasv[e] + prebuf[pp * 512 + (jg * 4 + e) * 32 + b_r]);
        unsigned hi0 = pack_bf16(h_[0], h_[1]), hi1 = pack_bf16(h_[2], h_[3]);
        unsigned lo0 = pack_bf16(h_[0] - bflo(hi0), h_[1] - bfhi(hi0));
        unsigned lo1 = pack_bf16(h_[2] - bflo(hi1), h_[3] - bfhi(hi1));
        u32x2 hp; hp[0] = hi0; hp[1] = hi1;
        u32x2 lp; lp[0] = lo0; lp[1] = lo1;
        unsigned* dp = (unsigned*)ws + H1R + (t & 1) * 32768 +
                       ((jcol0 >> 3) * 32 + b_r) * 4 + ((jcol0 >> 1) & 3);
        asm volatile("global_store_dwordx2 %0, %1, off sc0 sc1" ::"v"(dp), "v"(hp) : "memory");
        asm volatile("global_store_dwordx2 %0, %1, off sc0 sc1" ::"v"(dp + 16384), "v"(lp) : "memory");
        lg0 += h_[0]*wc0[0] + h_[1]*wc0[1] + h_[2]*wc0[2] + h_[3]*wc0[3];
        lg1 += h_[0]*wc1[0] + h_[1]*wc1[1] + h_[2]*wc1[2] + h_[3]*wc1[3];
        if (t == NT - 1) {
          f4 o; o[0]=h_[0]; o[1]=h_[1]; o[2]=h_[2]; o[3]=h_[3];
          *(f4*)(out + 64 + 32768 + (size_t)b_r * 1024 + jcol0) = o;
        }
      }
      asm volatile("s_waitcnt vmcnt(0)");
      __syncthreads();
      if (tid == 0) st_cohu(&flag1[(bid - 64) * 32], (unsigned)(t + 1));

      if (t < NT - 1) {  // tail: Wih1 x h0(t+1) -> prebuf[pp^1]
        if (tid < 64) { while (ld_flag(&flag0[tid * 32]) < t + 2) {} }
        __syncthreads();
        __builtin_amdgcn_sched_barrier(0);
        const f4* gph = wsf4 + (H0R >> 2) + ((t + 1) & 3) * 8192 + ch0 * 32 + bcol;
        const f4* gpl = gph + 4096;
        f4 gh[8], gl[8];
        LD16(gh, gl, gph, gpl)
        f4 cp = (f4)0.f;
        KT_G(0, 14) KT_G(1, 12) KT_G(2, 10) KT_G(3, 8)
        KT_G(4, 6)  KT_G(5, 4)  KT_G(6, 2)  KT_G(7, 0)
        partP[(ks * 2 + nt) * 64 + l] = cp;
        __syncthreads();
        if (tid >= 128 && tid < 256) {
          f4 sum = partP[ntr * 64 + rr] + partP[(2 + ntr) * 64 + rr] +
                   partP[(4 + ntr) * 64 + rr] + partP[(6 + ntr) * 64 + rr];
          #pragma unroll
          for (int e = 0; e < 4; ++e)
            prebuf[(pp ^ 1) * 512 + (jg * 4 + e) * 32 + b_r] = sum[e];
        }
      }
    }
    // ---- logits partials ----
    float* lgred = (float*)(w4 + 8192);
    __syncthreads();
    if (tid < 128) {
      lgred[jg * 32 + b_r] = lg0;
      lgred[128 + jg * 32 + b_r] = lg1;
    }
    __syncthreads();
    if (tid < 64) {
      const int c = tid >> 5, bb = tid & 31;
      float v = 0.f;
      #pragma unroll
      for (int g2 = 0; g2 < 4; ++g2) v += lgred[c * 128 + g2 * 32 + bb];
      st_cohf(&ws[PLOG + (size_t)(bid - 64) * 64 + c * 32 + bb], v);
    }
    __syncthreads();
    if (tid == 0) st_cohu(&flag1[(bid - 64) * 32], 600u);
  }

  // ---- final logits aggregation (block 0, an L0 block) ----
  if (bid == 0) {
    if (tid < 64) { while (ld_flag(&flag1[tid * 32]) < 600) {} }
    __syncthreads();
    __builtin_amdgcn_sched_barrier(0);
    float* lgred = (float*)(w4 + 8192);
    if (tid < 256) {
      const int g2 = tid >> 6, pair = tid & 63;
      float v = 0.f;
      for (int blk = g2; blk < 64; blk += 4)
        v += __hip_atomic_load(&ws[PLOG + (size_t)blk * 64 + pair],
                               __ATOMIC_RELAXED, __HIP_MEMORY_SCOPE_AGENT);
      lgred[tid] = v;
    }
    __syncthreads();
    if (tid < 64) {
      float s2 = bcls[tid >> 5];
      #pragma unroll
      for (int g2 = 0; g2 < 4; ++g2) s2 += lgred[g2 * 64 + tid];
      out[(size_t)(tid & 31) * 2 + (tid >> 5)] = s2;  // logits [B,C]
    }
  }
}

extern "C" void kernel_launch(void* const* d_in, const int* in_sizes, int n_in,
                              void* d_out, int out_size, void* d_ws, size_t ws_size,
                              hipStream_t stream) {
  const float* x    = (const float*)d_in[0];
  const float* h0   = (const float*)d_in[1];
  const float* Wih0 = (const float*)d_in[2];
  const float* Whh0 = (const float*)d_in[3];
  const float* bih0 = (const float*)d_in[4];
  const float* bhh0 = (const float*)d_in[5];
  const float* Wih1 = (const float*)d_in[6];
  const float* Whh1 = (const float*)d_in[7];
  const float* bih1 = (const float*)d_in[8];
  const float* bhh1 = (const float*)d_in[9];
  const float* Wcls = (const float*)d_in[10];
  const float* bcls = (const float*)d_in[11];
  float* out = (float*)d_out;
  float* ws  = (float*)d_ws;

  hipFuncSetAttribute((const void*)rnn_kernel,
                      hipFuncAttributeMaxDynamicSharedMemorySize, 151552);

  hipLaunchKernelGGL(wconv_kernel, dim3(4096), dim3(128), 0, stream,
                     Whh0, Wih0, Wih1, Whh1, ws);
  hipLaunchKernelGGL(xconv_kernel, dim3(512), dim3(128), 0, stream, x, ws);
  hipLaunchKernelGGL(hinit_kernel, dim3(32), dim3(256), 0, stream, h0, ws);

  void* args[] = { (void*)&bih0, (void*)&bhh0, (void*)&bih1, (void*)&bhh1,
                   (void*)&Wcls, (void*)&bcls, (void*)&out, (void*)&ws };
  hipLaunchCooperativeKernel((void*)rnn_kernel, dim3(128), dim3(512), args,
                             151552, stream);
}